// Round 9
// baseline (2285.638 us; speedup 1.0000x reference)
//
#include <hip/hip_runtime.h>
#include <cstdint>
#include <cstddef>

typedef _Float16 f16;
typedef _Float16 f16x4 __attribute__((ext_vector_type(4)));
typedef _Float16 f16x8 __attribute__((ext_vector_type(8)));
typedef float f32x4 __attribute__((ext_vector_type(4)));

// ---------- sizes ----------
#define SEQ 1024
#define BATCH 128
#define INDIM 256
#define HDIM 512
#define MROWS (SEQ * BATCH)          // 131072
#define NCOLS (3 * HDIM)             // 1536
#define BHDIM (BATCH * HDIM)         // 65536
#define TCHUNK 128
#define CHROWS (TCHUNK * BATCH)      // 16384

// workspace layout (bytes); total 506,730,496
#define P32_OFF   0ull                         // [16384][1536] f32 = 100,663,296
#define XHI_OFF   100663296ull                 // [131072][256] f16 = 67,108,864
#define XLO_OFF   167772160ull                 // [131072][256] f16 = 67,108,864
#define Y0HI_OFF  234881024ull                 // [131072][512] f16 = 134,217,728
#define Y0LO_OFF  369098752ull                 // [131072][512] f16 = 134,217,728
#define WHI_OFF   503316480ull                 // [1536][512] f16   = 1,572,864
#define WLO_OFF   504889344ull                 // [1536][512] f16   = 1,572,864
#define BIAS_OFF  506462208ull                 // [1536] f32
#define HST_OFF   506468352ull                 // [65536] f32
#define WS_NEEDED 506730496ull

__device__ __forceinline__ float fast_tanh(float x) {
  return 1.0f - 2.0f / (__expf(2.0f * x) + 1.0f);
}
__device__ __forceinline__ float fast_sigmoid(float x) {
  return 1.0f / (1.0f + __expf(-x));
}

// ---------- f32 -> (hi f16, lo' f16 = (v-hi)*2048) split ----------
__global__ __launch_bounds__(256) void split_kernel(const float* __restrict__ in,
                                                    f16* __restrict__ hi,
                                                    f16* __restrict__ lo, int n4) {
  int stride = gridDim.x * blockDim.x;
  for (int i = blockIdx.x * blockDim.x + threadIdx.x; i < n4; i += stride) {
    float4 v = reinterpret_cast<const float4*>(in)[i];
    f16x4 h4 = {(f16)v.x, (f16)v.y, (f16)v.z, (f16)v.w};
    f16x4 l4 = {(f16)((v.x - (float)h4[0]) * 2048.0f),
                (f16)((v.y - (float)h4[1]) * 2048.0f),
                (f16)((v.z - (float)h4[2]) * 2048.0f),
                (f16)((v.w - (float)h4[3]) * 2048.0f)};
    reinterpret_cast<f16x4*>(hi)[i] = h4;
    reinterpret_cast<f16x4*>(lo)[i] = l4;
  }
}

// ---------- GEMM: P[CHROWS,1536](f32) = (Ahi+Alo/2048).(Whi+Wlo/2048)^T + bias ----------
// T14 reg-staged async split + PADDED (conflict-free-read) LDS, double-buffered:
//   iter t: issue 8 global 16B loads (tile t+1) -> regs | ds_read+48 MFMA on buf[cur]
//           | ds_write tile t+1 into buf[cur^1] (vmcnt waits auto-inserted)
//           | one __syncthreads.
// Padded stride 40 f16 = 80B: read banks (20*row)%32 cover all 32 banks over 8 rows ->
// conflict-free ds_read_b128 (the linear 64B-row layout of r5-r8 was 8-way conflicted).
// LDS = 2 x 4 x 10KB = 80KB -> 2 blocks/CU.
__global__ __launch_bounds__(256, 2) void gemm_split_kernel(
    const f16* __restrict__ Ahi, const f16* __restrict__ Alo,
    const f16* __restrict__ Whi, const f16* __restrict__ Wlo,
    const float* __restrict__ bias, float* __restrict__ P, int K) {
  constexpr int BK = 32;
  constexpr int LDSS = BK + 8;  // 40 f16 = 80 B row stride
  __shared__ f16 sAh[2][128 * LDSS];
  __shared__ f16 sAl[2][128 * LDSS];
  __shared__ f16 sBh[2][128 * LDSS];
  __shared__ f16 sBl[2][128 * LDSS];

  const int tid = threadIdx.x;
  const int lane = tid & 63;
  const int w = tid >> 6;
  const int wm = (w >> 1) * 64;
  const int wn = (w & 1) * 64;

  // XCD-aware bijective swizzle (gridDim.x = 1536, %8 == 0), n-block fastest
  const int per = gridDim.x >> 3;
  const int logical = (blockIdx.x & 7) * per + (blockIdx.x >> 3);
  const int nb = logical % (NCOLS / 128);
  const int mb = logical / (NCOLS / 128);
  const long m0 = (long)mb * 128;
  const int n0 = nb * 128;

  const int fr = lane & 15;
  const int fk = (lane >> 4) * 8;

  // staging indices (r2-proven): tile 128x32 f16 = 8KB; 256 threads x 2 rounds x 16B.
  // round r: idx = r*256+tid, row = idx>>2 (4 threads/row), c8 = (idx&3)*8.
  const int row0 = tid >> 2,        c80 = (tid & 3) << 3;
  const int row1 = (256 + tid) >> 2, c81 = c80;  // (256+tid)&3 == tid&3
  const long ga0 = (m0 + row0) * (long)K + c80;
  const long ga1 = (m0 + row1) * (long)K + c81;
  const long gb0 = (n0 + row0) * (long)K + c80;
  const long gb1 = (n0 + row1) * (long)K + c81;
  const int la0 = row0 * LDSS + c80;
  const int la1 = row1 * LDSS + c81;

  f32x4 acc[4][4] = {};
  f32x4 accc[4][4] = {};

  const int NT = K / BK;

  f16x8 rAh0, rAh1, rAl0, rAl1, rBh0, rBh1, rBl0, rBl1;

#define LOADR(tt)                                                           \
  do {                                                                      \
    const int k0 = (tt) * BK;                                               \
    rAh0 = *reinterpret_cast<const f16x8*>(Ahi + ga0 + k0);                 \
    rAh1 = *reinterpret_cast<const f16x8*>(Ahi + ga1 + k0);                 \
    rAl0 = *reinterpret_cast<const f16x8*>(Alo + ga0 + k0);                 \
    rAl1 = *reinterpret_cast<const f16x8*>(Alo + ga1 + k0);                 \
    rBh0 = *reinterpret_cast<const f16x8*>(Whi + gb0 + k0);                 \
    rBh1 = *reinterpret_cast<const f16x8*>(Whi + gb1 + k0);                 \
    rBl0 = *reinterpret_cast<const f16x8*>(Wlo + gb0 + k0);                 \
    rBl1 = *reinterpret_cast<const f16x8*>(Wlo + gb1 + k0);                 \
  } while (0)
#define WRITEB(buf)                                                         \
  do {                                                                      \
    *reinterpret_cast<f16x8*>(&sAh[(buf)][la0]) = rAh0;                     \
    *reinterpret_cast<f16x8*>(&sAh[(buf)][la1]) = rAh1;                     \
    *reinterpret_cast<f16x8*>(&sAl[(buf)][la0]) = rAl0;                     \
    *reinterpret_cast<f16x8*>(&sAl[(buf)][la1]) = rAl1;                     \
    *reinterpret_cast<f16x8*>(&sBh[(buf)][la0]) = rBh0;                     \
    *reinterpret_cast<f16x8*>(&sBh[(buf)][la1]) = rBh1;                     \
    *reinterpret_cast<f16x8*>(&sBl[(buf)][la0]) = rBl0;                     \
    *reinterpret_cast<f16x8*>(&sBl[(buf)][la1]) = rBl1;                     \
  } while (0)

  // prologue: stage tile 0
  LOADR(0);
  WRITEB(0);
  __syncthreads();

  int cur = 0;
  for (int t = 0; t < NT; ++t) {
    const bool pf = (t + 1) < NT;
    if (pf) LOADR(t + 1);  // issue early; lands during this tile's compute

    f16x8 ah[4], al[4], bh[4], bl[4];
#pragma unroll
    for (int i = 0; i < 4; ++i) {
      ah[i] = *reinterpret_cast<const f16x8*>(&sAh[cur][(wm + i * 16 + fr) * LDSS + fk]);
      al[i] = *reinterpret_cast<const f16x8*>(&sAl[cur][(wm + i * 16 + fr) * LDSS + fk]);
      bh[i] = *reinterpret_cast<const f16x8*>(&sBh[cur][(wn + i * 16 + fr) * LDSS + fk]);
      bl[i] = *reinterpret_cast<const f16x8*>(&sBl[cur][(wn + i * 16 + fr) * LDSS + fk]);
    }

    __builtin_amdgcn_s_setprio(1);
#pragma unroll
    for (int i = 0; i < 4; ++i)
#pragma unroll
      for (int j = 0; j < 4; ++j) {
        acc[i][j]  = __builtin_amdgcn_mfma_f32_16x16x32_f16(ah[i], bh[j], acc[i][j], 0, 0, 0);
        accc[i][j] = __builtin_amdgcn_mfma_f32_16x16x32_f16(ah[i], bl[j], accc[i][j], 0, 0, 0);
        accc[i][j] = __builtin_amdgcn_mfma_f32_16x16x32_f16(al[i], bh[j], accc[i][j], 0, 0, 0);
      }
    __builtin_amdgcn_s_setprio(0);

    if (pf) {
      WRITEB(cur ^ 1);   // compiler inserts the needed vmcnt waits before each write
      __syncthreads();   // ds_writes drained (lgkmcnt) + all waves flip together
      cur ^= 1;
    }
  }
#undef LOADR
#undef WRITEB

  // epilogue: C/D layout col = lane&15, row = (lane>>4)*4 + reg
  const int crow = (lane >> 4) * 4;
  const int ccol = lane & 15;
#pragma unroll
  for (int j = 0; j < 4; ++j) {
    int gc = n0 + wn + j * 16 + ccol;
    float bv = bias[gc];
#pragma unroll
    for (int i = 0; i < 4; ++i) {
      long gr = m0 + wm + i * 16 + crow;
#pragma unroll
      for (int r = 0; r < 4; ++r) {
        P[(gr + r) * NCOLS + gc] = acc[i][j][r] + accc[i][j][r] * (1.0f / 2048.0f) + bv;
      }
    }
  }
}

// ---------- BRC scan over one t-chunk: one thread per (b,h) chain ----------
// ALL output pointers are pre-offset by the caller to this chunk's base.
__global__ __launch_bounds__(256) void scan_kernel(
    const float* __restrict__ P, const float* __restrict__ hinit,
    float* __restrict__ hstate, int first,
    const float* __restrict__ wc, const float* __restrict__ wa,
    f16* __restrict__ Yhi, f16* __restrict__ Ylo,   // layer-0 split outputs (or null)
    float* __restrict__ Yf,                          // layer-1 f32 output (or null)
    float* __restrict__ HN) {
  const int j = blockIdx.x * 256 + threadIdx.x;  // 0..65535
  const int hh = j & (HDIM - 1);
  float h = first ? hinit[j] : hstate[j];
  const float wcv = wc[hh];
  const float wav = wa[hh];
  const float* p = P + (long)(j >> 9) * NCOLS + hh;
  long yo = j;
#pragma unroll 4
  for (int t = 0; t < TCHUNK; ++t) {
    float pc = p[0];
    float pa = p[HDIM];
    float ph = p[2 * HDIM];
    float c = fast_sigmoid(fmaf(wcv, h, pc));
    float a = 1.0f + fast_tanh(fmaf(wav, h, pa));
    h = c * h + (1.0f - c) * fast_tanh(fmaf(a, h, ph));
    if (Yhi) {
      f16 hv = (f16)h;
      Yhi[yo] = hv;
      Ylo[yo] = (f16)((h - (float)hv) * 2048.0f);
    }
    if (Yf) Yf[yo] = h;
    yo += BHDIM;
    p += BATCH * NCOLS;
  }
  hstate[j] = h;
  if (HN) HN[j] = h;
}

extern "C" void kernel_launch(void* const* d_in, const int* in_sizes, int n_in,
                              void* d_out, int out_size, void* d_ws, size_t ws_size,
                              hipStream_t stream) {
  const float* x   = (const float*)d_in[0];
  const float* h0  = (const float*)d_in[1];
  const float* Uc0 = (const float*)d_in[2];
  const float* wc0 = (const float*)d_in[3];
  const float* bc0 = (const float*)d_in[4];
  const float* Ua0 = (const float*)d_in[5];
  const float* wa0 = (const float*)d_in[6];
  const float* ba0 = (const float*)d_in[7];
  const float* Uh0 = (const float*)d_in[8];
  const float* bh0 = (const float*)d_in[9];
  const float* Uc1 = (const float*)d_in[10];
  const float* wc1 = (const float*)d_in[11];
  const float* bc1 = (const float*)d_in[12];
  const float* Ua1 = (const float*)d_in[13];
  const float* wa1 = (const float*)d_in[14];
  const float* ba1 = (const float*)d_in[15];
  const float* Uh1 = (const float*)d_in[16];
  const float* bh1 = (const float*)d_in[17];

  if (ws_size < WS_NEEDED) return;

  char* ws = (char*)d_ws;
  float* p32  = (float*)(ws + P32_OFF);
  f16* xhi    = (f16*)(ws + XHI_OFF);
  f16* xlo    = (f16*)(ws + XLO_OFF);
  f16* y0hi   = (f16*)(ws + Y0HI_OFF);
  f16* y0lo   = (f16*)(ws + Y0LO_OFF);
  f16* whi    = (f16*)(ws + WHI_OFF);
  f16* wlo    = (f16*)(ws + WLO_OFF);
  float* bias = (float*)(ws + BIAS_OFF);
  float* hst  = (float*)(ws + HST_OFF);

  float* y1  = (float*)d_out;
  float* hn0 = y1 + (long)SEQ * BHDIM;
  float* hn1 = hn0 + BHDIM;

  const int NCH = SEQ / TCHUNK;  // 8
  const dim3 gemm_grid(CHROWS / 128 * (NCOLS / 128));  // 1536, %8==0

  // ---- pre-split x ----
  hipLaunchKernelGGL(split_kernel, dim3(2048), dim3(256), 0, stream, x, xhi, xlo,
                     MROWS * INDIM / 4);

  // ---- layer 0 weights/bias (K=256) ----
  hipLaunchKernelGGL(split_kernel, dim3(128), dim3(256), 0, stream, Uc0,
                     whi + 0 * HDIM * INDIM, wlo + 0 * HDIM * INDIM, HDIM * INDIM / 4);
  hipLaunchKernelGGL(split_kernel, dim3(128), dim3(256), 0, stream, Ua0,
                     whi + 1 * HDIM * INDIM, wlo + 1 * HDIM * INDIM, HDIM * INDIM / 4);
  hipLaunchKernelGGL(split_kernel, dim3(128), dim3(256), 0, stream, Uh0,
                     whi + 2 * HDIM * INDIM, wlo + 2 * HDIM * INDIM, HDIM * INDIM / 4);
  hipMemcpyAsync(bias + 0 * HDIM, bc0, HDIM * sizeof(float), hipMemcpyDeviceToDevice, stream);
  hipMemcpyAsync(bias + 1 * HDIM, ba0, HDIM * sizeof(float), hipMemcpyDeviceToDevice, stream);
  hipMemcpyAsync(bias + 2 * HDIM, bh0, HDIM * sizeof(float), hipMemcpyDeviceToDevice, stream);

  // ---- layer 0: chunked GEMM + scan ----
  for (int tc = 0; tc < NCH; ++tc) {
    hipLaunchKernelGGL(gemm_split_kernel, gemm_grid, dim3(256), 0, stream,
                       xhi + (long)tc * CHROWS * INDIM, xlo + (long)tc * CHROWS * INDIM,
                       whi, wlo, bias, p32, INDIM);
    hipLaunchKernelGGL(scan_kernel, dim3(BHDIM / 256), dim3(256), 0, stream,
                       p32, h0, hst, (tc == 0) ? 1 : 0, wc0, wa0,
                       y0hi + (long)tc * TCHUNK * BHDIM, y0lo + (long)tc * TCHUNK * BHDIM,
                       (float*)nullptr, (tc == NCH - 1) ? hn0 : (float*)nullptr);
  }

  // ---- layer 1 weights/bias (K=512) ----
  hipLaunchKernelGGL(split_kernel, dim3(256), dim3(256), 0, stream, Uc1,
                     whi + 0 * HDIM * HDIM, wlo + 0 * HDIM * HDIM, HDIM * HDIM / 4);
  hipLaunchKernelGGL(split_kernel, dim3(256), dim3(256), 0, stream, Ua1,
                     whi + 1 * HDIM * HDIM, wlo + 1 * HDIM * HDIM, HDIM * HDIM / 4);
  hipLaunchKernelGGL(split_kernel, dim3(256), dim3(256), 0, stream, Uh1,
                     whi + 2 * HDIM * HDIM, wlo + 2 * HDIM * HDIM, HDIM * HDIM / 4);
  hipMemcpyAsync(bias + 0 * HDIM, bc1, HDIM * sizeof(float), hipMemcpyDeviceToDevice, stream);
  hipMemcpyAsync(bias + 1 * HDIM, ba1, HDIM * sizeof(float), hipMemcpyDeviceToDevice, stream);
  hipMemcpyAsync(bias + 2 * HDIM, bh1, HDIM * sizeof(float), hipMemcpyDeviceToDevice, stream);

  // ---- layer 1: chunked GEMM + scan ----
  for (int tc = 0; tc < NCH; ++tc) {
    hipLaunchKernelGGL(gemm_split_kernel, gemm_grid, dim3(256), 0, stream,
                       y0hi + (long)tc * CHROWS * HDIM, y0lo + (long)tc * CHROWS * HDIM,
                       whi, wlo, bias, p32, HDIM);
    hipLaunchKernelGGL(scan_kernel, dim3(BHDIM / 256), dim3(256), 0, stream,
                       p32, h0 + BHDIM, hst, (tc == 0) ? 1 : 0, wc1, wa1,
                       (f16*)nullptr, (f16*)nullptr, y1 + (long)tc * TCHUNK * BHDIM,
                       (tc == NCH - 1) ? hn1 : (float*)nullptr);
  }
}